// Round 11
// baseline (213.051 us; speedup 1.0000x reference)
//
#include <hip/hip_runtime.h>
#include <hip/hip_fp16.h>
#include <math.h>

// LinearCaps2d, BATCH=256, N = B_TYPES*H*W = 2048, C=10, POSE=16, 3 routing iters.
// R23: delete the weight LDS round-trip entirely. Evidence (R12-R22): per-pass
// ~47us invariant to grid/occupancy/softmax/atomics/staging-mechanism/barriers;
// pass0 (VALU 11%) == pass2 (VALU 29%) at identical duration -> the binder is
// the staged-pipeline latency chain, not any compute pipe.
// Key observation: each lane's MFMA A-fragment W[n][c][o=lo][i=q*4..+3] is a
// CONTIGUOUS coalesced 1KB chunk per (n,c) across the wave -> direct
// global_load_dwordx4 needs no LDS, no cvt-store, no barrier. L2 absorbs the
// 16-way re-read (160KB slice/ngrp << 4MB/XCD).
//   (1) weights: direct global->reg, 1-n-ahead prefetch (wreg[10] float4;
//       cvt to awh[10] f16x4 at n-start, then issue n+1's batch);
//   (2) poses: staged to LDS ONCE for all 16 n (they are not per-fragment
//       coalescible); ONE barrier per kernel, zero in the main loop -> waves
//       free-run, no lockstep drain;
//   (3) transpose scratch reuses each wave's own xs rows (wave-private, no
//       barrier); LDS total 34304 B;
//   (4) __launch_bounds__(256,1): session law regs=256/arg -> cap 256;
//       usage ~160 -> no spill (WRITE>32MB = tripwire), HW ~3 waves/SIMD.
// Math identical to R20/R22 (fragment values bit-identical). ws: s0,s1,s2.

typedef _Float16 f16;
typedef _Float16 f16x2 __attribute__((ext_vector_type(2)));
typedef _Float16 f16x4 __attribute__((ext_vector_type(4)));
typedef __fp16   h16x2 __attribute__((ext_vector_type(2)));
typedef float f32x4 __attribute__((ext_vector_type(4)));

__device__ __forceinline__ f16x2 pk(float a, float b) {
    h16x2 t = __builtin_amdgcn_cvt_pkrtz(a, b);
    return __builtin_bit_cast(f16x2, t);
}

#if __has_builtin(__builtin_amdgcn_fdot2)
__device__ __forceinline__ float FDOT2(f16x2 a, f16x2 b, float c) {
    return __builtin_amdgcn_fdot2(__builtin_bit_cast(h16x2, a),
                                  __builtin_bit_cast(h16x2, b), c, false);
}
#else
__device__ __forceinline__ float FDOT2(f16x2 a, f16x2 b, float c) {
    return c + (float)a[0] * (float)b[0] + (float)a[1] * (float)b[1];
}
#endif

// xs row stride in f16: 268 -> dword stride 134 === 6 (mod 32), same verified
// low-conflict residue class as R7's XS_ROW=76 (38 dwords === 6 mod 32).
constexpr int XR = 268;

__device__ __forceinline__ float xorsum4(float v) {
    v += __shfl_xor(v, 16, 64);
    v += __shfl_xor(v, 32, 64);
    return v;
}

// packed f16x2 cross-quad reduction: one shfl pair for two c's (verified R11)
__device__ __forceinline__ f16x2 xorsum4h(f16x2 v) {
    union { f16x2 h; int i; } u;
    union { int i; f16x2 h; } w;
    u.h = v; w.i = __shfl_xor(u.i, 16, 64); v = v + w.h;
    u.h = v; w.i = __shfl_xor(u.i, 32, 64); v = v + w.h;
    return v;
}

__device__ __forceinline__ f16x4 cvt4(float4 w) {
    f16x2 a = pk(w.x, w.y);
    f16x2 b = pk(w.z, w.w);
    f16x4 r; r[0] = a[0]; r[1] = a[1]; r[2] = b[0]; r[3] = b[1];
    return r;
}

// grid: 512 blocks = 128 n-groups (16 n) x 4 b-groups (64 b); 256 thr = 4 waves.
template<int PASS>
__global__ __launch_bounds__(256, 1)
void pass_k(const float* __restrict__ poses, const float* __restrict__ weight,
            const float* __restrict__ bias,
            const float* __restrict__ sp0, const float* __restrict__ sp1,
            float* __restrict__ s_dst)
{
    __shared__ f16 xs[64 * XR];   // 34304 B: 64 b x (16 n x 16 i) f16, padded rows

    const int tid  = threadIdx.x;
    const int blk  = blockIdx.x;
    const int ngrp = blk >> 2;          // 128 n-groups (16 n each)
    const int b0   = (blk & 3) * 64;    // 4 b-groups
    const int wave = tid >> 6;
    const int lane = tid & 63;
    const int q    = lane >> 4;
    const int lo   = lane & 15;
    const int wtb  = wave * 16;
    const int bg   = b0 + wtb;          // wave's global batch base

    // ---- direct weight fragments: lane's (n,c) chunk is contiguous 16 B at
    // wfrag + (n*10+c)*256; across the wave = coalesced 1 KB per (n,c).
    const float* wfrag = weight + (size_t)ngrp * 40960 + lo * 16 + q * 4;
    float4 wreg[10];
    auto load_wn = [&](int n) {
        #pragma unroll
        for (int c = 0; c < 10; ++c)
            wreg[c] = *(const float4*)(wfrag + (size_t)(n * 10 + c) * 256);
    };

    // hoist n=0 weight loads: HBM latency hides under xs staging + vsp preamble.
    load_wn(0);

    // ---- stage ALL poses for this block once: 64 b x 16 n x 16 i.
    // thread (b_loc, part): 16 contiguous float4 (= 4 n's worth), coalesced.
    const int b_loc = tid >> 2, part = tid & 3;
    {
        const float* xp = poses + (size_t)(b0 + b_loc) * 32768
                          + (size_t)ngrp * 256 + part * 64;
        float4 xr0[8], xr1[8];
        #pragma unroll
        for (int j = 0; j < 8; ++j) xr0[j] = ((const float4*)xp)[j];
        #pragma unroll
        for (int j = 0; j < 8; ++j) xr1[j] = ((const float4*)xp)[8 + j];
        f16* lp = xs + b_loc * XR + part * 64;
        #pragma unroll
        for (int j = 0; j < 8; ++j) *(f16x4*)&lp[j * 4] = cvt4(xr0[j]);
        #pragma unroll
        for (int j = 0; j < 8; ++j) *(f16x4*)&lp[32 + j * 4] = cvt4(xr1[j]);
    }

    // ---- inline squash: vsp[c] = v[b=bg+lo][c][o=q*4..q*4+3], packed f16
    f16x2 vsp[10][2];
    if (PASS >= 1) {
        const int rowb = (bg + lo) * 10;
        #pragma unroll
        for (int c = 0; c < 10; ++c) {
            float4 bb = *(const float4*)(bias + c * 16 + q * 4);
            float4 sa = *(const float4*)(sp0 + (size_t)(rowb + c) * 16 + q * 4);
            float t0 = sa.x + bb.x, t1 = sa.y + bb.y, t2 = sa.z + bb.z, t3 = sa.w + bb.w;
            float n2 = xorsum4(t0*t0 + t1*t1 + t2*t2 + t3*t3);
            float sc = n2 / (1.f + n2) * rsqrtf(n2 + 1e-8f);
            float v0 = sc*t0, v1 = sc*t1, v2 = sc*t2, v3 = sc*t3;
            if (PASS == 2) {
                float4 sb = *(const float4*)(sp1 + (size_t)(rowb + c) * 16 + q * 4);
                float u0 = sb.x + bb.x, u1 = sb.y + bb.y, u2 = sb.z + bb.z, u3 = sb.w + bb.w;
                float m2 = xorsum4(u0*u0 + u1*u1 + u2*u2 + u3*u3);
                float sc2 = m2 / (1.f + m2) * rsqrtf(m2 + 1e-8f);
                v0 += sc2*u0; v1 += sc2*u1; v2 += sc2*u2; v3 += sc2*u3;
            }
            vsp[c][0] = pk(v0, v1);
            vsp[c][1] = pk(v2, v3);
        }
    }

    f32x4 acc[10];
    #pragma unroll
    for (int c = 0; c < 10; ++c) acc[c] = (f32x4){0.f, 0.f, 0.f, 0.f};

    __syncthreads();   // xs ready -- the ONLY barrier in this kernel

    // ---- main loop: 16 n, zero barriers, waves free-run.
    #pragma unroll 2
    for (int n = 0; n < 16; ++n) {
        // consume wreg -> f16 fragments, then immediately issue n+1's batch.
        f16x4 awh[10];
        #pragma unroll
        for (int c = 0; c < 10; ++c) awh[c] = cvt4(wreg[c]);
        if (n < 15) load_wn(n + 1);

        f16x4 bx = *(const f16x4*)&xs[(wtb + lo) * XR + n * 16 + q * 4];
        f16x2 Vh[10][2];
        #pragma unroll
        for (int c = 0; c < 10; ++c) {
            f32x4 V = __builtin_amdgcn_mfma_f32_16x16x16f16(
                awh[c], bx, (f32x4){0.f, 0.f, 0.f, 0.f}, 0, 0, 0);
            Vh[c][0] = pk(V[0], V[1]);
            Vh[c][1] = pk(V[2], V[3]);
        }

        float cfv[10];
        if (PASS >= 1) {
            // logits: fdot2 on packed votes vs vsp; packed cross-quad reduce
            float lg[10];
            #pragma unroll
            for (int cp = 0; cp < 5; ++cp) {
                const int c0 = cp * 2, c1 = cp * 2 + 1;
                float p0 = FDOT2(Vh[c0][0], vsp[c0][0], 0.f);
                p0 = FDOT2(Vh[c0][1], vsp[c0][1], p0);
                float p1 = FDOT2(Vh[c1][0], vsp[c1][0], 0.f);
                p1 = FDOT2(Vh[c1][1], vsp[c1][1], p1);
                f16x2 pr = xorsum4h(pk(p0, p1));
                lg[c0] = (float)pr[0];
                lg[c1] = (float)pr[1];
            }
            float m = lg[0];
            #pragma unroll
            for (int c = 1; c < 10; ++c) m = fmaxf(m, lg[c]);
            float sum = 0.f;
            #pragma unroll
            for (int c = 0; c < 10; ++c) { lg[c] = __expf(lg[c] - m); sum += lg[c]; }
            const float inv = 1.f / sum;
            #pragma unroll
            for (int c = 0; c < 10; ++c) cfv[c] = lg[c] * inv;
        }

        // s-accumulate straight from packed votes
        #pragma unroll
        for (int c = 0; c < 10; ++c) {
            const float w = (PASS == 0) ? 1.f : cfv[c];
            acc[c][0] = fmaf(w, (float)Vh[c][0][0], acc[c][0]);
            acc[c][1] = fmaf(w, (float)Vh[c][0][1], acc[c][1]);
            acc[c][2] = fmaf(w, (float)Vh[c][1][0], acc[c][2]);
            acc[c][3] = fmaf(w, (float)Vh[c][1][1], acc[c][3]);
        }
    }

    // ---- wave-local LDS transpose (b<->o) + full-line atomic flush.
    // Reuse this wave's OWN xs rows (8576 B >= 1280 B needed): the wave's last
    // xs read (n=15) precedes these writes in program order (in-order DS);
    // other waves never touch this region. No barrier needed.
    float* trw = (float*)&xs[(size_t)wtb * XR];   // 16-B aligned (wave*8576)
    const float fs = (PASS == 0) ? 0.1f : 1.f;
    #pragma unroll
    for (int c = 0; c < 10; ++c) {
        // write own (b=lo, o=q*4..q*4+3); 16B-aligned b128
        *(float4*)&trw[lo * 20 + q * 4] = (float4){acc[c][0], acc[c][1], acc[c][2], acc[c][3]};
        // read (b=q*4+r, o=lo) -- wave-synchronous, in-order DS ops
        float r0 = trw[(q * 4 + 0) * 20 + lo];
        float r1 = trw[(q * 4 + 1) * 20 + lo];
        float r2 = trw[(q * 4 + 2) * 20 + lo];
        float r3 = trw[(q * 4 + 3) * 20 + lo];
        float* sp = s_dst + ((size_t)(bg + q * 4) * 10 + c) * 16 + lo;
        unsafeAtomicAdd(sp + 0 * 160, fs * r0);
        unsafeAtomicAdd(sp + 1 * 160, fs * r1);
        unsafeAtomicAdd(sp + 2 * 160, fs * r2);
        unsafeAtomicAdd(sp + 3 * 160, fs * r3);
    }
}

// final squash: 2560 rows, one (b,c) per thread (verified R3/R7).
__global__ __launch_bounds__(256)
void epi_k(const float* __restrict__ s2, const float* __restrict__ bias,
           float* __restrict__ out)
{
    const int t = blockIdx.x * 256 + threadIdx.x;
    if (t >= 2560) return;
    const int c = t % 10;
    const float* sp = s2 + (size_t)t * 16;
    const float* bp = bias + c * 16;
    float sv[16];
    float n2 = 0.f;
    #pragma unroll
    for (int o = 0; o < 16; ++o) { float v = sp[o] + bp[o]; sv[o] = v; n2 += v * v; }
    const float scale = n2 / (1.f + n2) * rsqrtf(n2 + 1e-8f);
    float a2 = 0.f;
    #pragma unroll
    for (int o = 0; o < 16; ++o) {
        float v = scale * sv[o];
        out[(size_t)t * 16 + o] = v;
        a2 += v * v;
    }
    out[40960 + t] = sqrtf(a2 + 1e-8f);
}

extern "C" void kernel_launch(void* const* d_in, const int* in_sizes, int n_in,
                              void* d_out, int out_size, void* d_ws, size_t ws_size,
                              hipStream_t stream)
{
    const float* poses  = (const float*)d_in[0];
    // d_in[1] (input_caps_activations) unused by the reference.
    const float* weight = (const float*)d_in[2];
    const float* bias   = (const float*)d_in[3];
    float* out = (float*)d_out;
    float* s0 = (float*)d_ws;
    float* s1 = s0 + 40960;
    float* s2 = s1 + 40960;

    (void)hipMemsetAsync(d_ws, 0, 3 * 40960 * sizeof(float), stream);

    pass_k<0><<<512, 256, 0, stream>>>(poses, weight, bias, nullptr, nullptr, s0);
    pass_k<1><<<512, 256, 0, stream>>>(poses, weight, bias, s0, nullptr, s1);
    pass_k<2><<<512, 256, 0, stream>>>(poses, weight, bias, s0, s1, s2);
    epi_k<<<10, 256, 0, stream>>>(s2, bias, out);
}